// Round 3
// baseline (432.917 us; speedup 1.0000x reference)
//
#include <hip/hip_runtime.h>
#include <math.h>

#define HH 512
#define WW 512
#define NB 64
#define HW (HH*WW)

struct GaussK { float k[13]; };

__device__ __forceinline__ float idenv(int i) {
    return (float)(2*i - (WW-1)) / (float)(WW-1);
}

#define DEF_OFF ((float)((2.0 + 4.0/511.0)/2.0))
#define BOUND   ((float)(2.0/512.0*8.0))

// ---------------- vertical blur of prim ch0 -> out plane 0 (float4) ----------------
__global__ void k_vblur(const float* __restrict__ prim, float* __restrict__ out, GaussK gk) {
    int idx = blockIdx.x*256 + threadIdx.x;          // over B*H*W/4
    int w4 = idx & 127;
    int h  = (idx >> 7) & (HH-1);
    int b  = idx >> 16;
    const float4* src = (const float4*)(prim + (size_t)b*2*HW);   // channel 0
    float4 acc = {0.f,0.f,0.f,0.f};
    #pragma unroll
    for (int i = 0; i < 13; ++i) {
        int hh = h - 6 + i;
        hh = hh < 0 ? -hh : (hh > HH-1 ? 2*(HH-1) - hh : hh);
        float4 v = src[(size_t)hh*128 + w4];
        acc.x = fmaf(gk.k[i], v.x, acc.x);
        acc.y = fmaf(gk.k[i], v.y, acc.y);
        acc.z = fmaf(gk.k[i], v.z, acc.z);
        acc.w = fmaf(gk.k[i], v.w, acc.w);
    }
    ((float4*)(out + (size_t)b*3*HW))[(size_t)h*128 + w4] = acc;
}

// ---------------- horizontal blur of prim ch1 -> out plane 1 (4 px/thread) ----------------
__global__ void k_hblur(const float* __restrict__ prim, float* __restrict__ out, GaussK gk) {
    int idx = blockIdx.x*256 + threadIdx.x;          // over B*H*W/4
    int w4 = idx & 127;
    int h  = (idx >> 7) & (HH-1);
    int b  = idx >> 16;
    const float* src = prim + ((size_t)b*2 + 1)*HW + (size_t)h*WW;
    float t[16];                                     // cols 4*w4-6 .. 4*w4+9
    #pragma unroll
    for (int j = 0; j < 16; ++j) {
        int x = w4*4 - 6 + j;
        x = x < 0 ? -x : (x > WW-1 ? 2*(WW-1) - x : x);
        t[j] = src[x];
    }
    float4 o;
    float* op = (float*)&o;
    #pragma unroll
    for (int j = 0; j < 4; ++j) {
        float acc = 0.f;
        #pragma unroll
        for (int i = 0; i < 13; ++i) acc = fmaf(gk.k[i], t[j+i], acc);
        op[j] = acc;
    }
    ((float4*)(out + ((size_t)b*3 + 1)*HW))[(size_t)h*128 + w4] = o;
}

// ---- fused horizontal blur + row scan (x channel), in-place on plane 0 ----
// one wave per (b,h) row; lane l owns columns 8l..8l+7
__global__ void k_xscan(float* __restrict__ out, GaussK gk) {
    __shared__ float row[528];   // row[8+x] = vblur value at column x, x in [-6, 517]
    int b = blockIdx.x >> 9;
    int h = blockIdx.x & (HH-1);
    float* plane0 = out + (size_t)b*3*HW + (size_t)h*WW;
    int lane = threadIdx.x;

    const float4* p4 = (const float4*)plane0;
    #pragma unroll
    for (int t = 0; t < 2; ++t) {
        int g = lane + 64*t;                 // 0..127
        float4 v = p4[g];
        row[8 + 4*g + 0] = v.x;
        row[8 + 4*g + 1] = v.y;
        row[8 + 4*g + 2] = v.z;
        row[8 + 4*g + 3] = v.w;
    }
    if (lane < 6) {
        row[2 + lane]   = plane0[6 - lane];      // cols -6..-1 reflected
        row[520 + lane] = plane0[510 - lane];    // cols 512..517 reflected
    }
    __syncthreads();

    // s for columns 8l-1 .. 8l+7 ; col -1 -> s = 0
    float s[9];
    int base = lane*8 - 1;
    #pragma unroll
    for (int j = 0; j < 9; ++j) {
        int wcol = base + j;
        float v = 0.f;
        if (wcol >= 0) {
            float acc = 0.f;
            #pragma unroll
            for (int i = 0; i < 13; ++i) acc = fmaf(gk.k[i], row[wcol + 2 + i], acc);
            v = acc + idenv(wcol) + DEF_OFF;
        }
        s[j] = v;
    }
    float qs[8];
    float q = 0.f;
    #pragma unroll
    for (int j = 1; j < 9; ++j) {
        q += fmaxf(s[j] - s[j-1], 0.f);
        qs[j-1] = q;
    }
    float inc = q;
    #pragma unroll
    for (int d = 1; d < 64; d <<= 1) {
        float t = __shfl_up(inc, d, 64);
        if (lane >= d) inc += t;
    }
    float excl = inc - q;

    float4 g0, g1;
    float* gp0 = (float*)&g0;
    float* gp1 = (float*)&g1;
    #pragma unroll
    for (int j = 0; j < 8; ++j) {
        int wcol = lane*8 + j;
        float sx = excl + qs[j];
        float p = sx - DEF_OFF - idenv(wcol);
        p = fminf(fmaxf(p, -BOUND), BOUND);
        float g = p + idenv(wcol);
        g = fminf(fmaxf(g, -1.f), 1.f);
        if (j < 4) gp0[j] = g; else gp1[j-4] = g;
    }
    *(float4*)(plane0 + lane*8)     = g0;
    *(float4*)(plane0 + lane*8 + 4) = g1;
}

// ---- fused vertical blur + column scan (y channel): read plane 1, write plane 2 ----
// block = 1024 threads = 16 waves; wave ws owns rows [ws*32, ws*32+32)
__global__ void __launch_bounds__(1024) k_yscan(float* __restrict__ out, GaussK gk) {
    __shared__ float segsum[16][64];
    int b    = blockIdx.x >> 3;          // 64*8 = 512 blocks
    int wt   = blockIdx.x & 7;
    int lane = threadIdx.x & 63;
    int ws   = threadIdx.x >> 6;         // 0..15
    int w    = wt*64 + lane;
    const float* p1 = out + ((size_t)b*3 + 1)*HW + w;
    float*       p2 = out + ((size_t)b*3 + 2)*HW + w;
    int r0 = ws*32;

    #define LDROW(r_) ({ int r = (r_); r = r < 0 ? -r : (r > HH-1 ? 2*(HH-1) - r : r); \
                         p1[(size_t)r*WW]; })

    // ---------- pass 1: per-segment partial sum ----------
    float qsum = 0.f;
    {
        float win[13], sprev;
        int h;
        if (ws == 0) {
            #pragma unroll
            for (int i = 0; i < 13; ++i) win[i] = LDROW(-6 + i);
            sprev = 0.f; h = 0;
        } else {
            #pragma unroll
            for (int i = 0; i < 13; ++i) win[i] = LDROW(r0 - 7 + i);
            float acc = 0.f;
            #pragma unroll
            for (int i = 0; i < 13; ++i) acc = fmaf(gk.k[i], win[i], acc);
            sprev = acc + idenv(r0 - 1) + DEF_OFF;
            #pragma unroll
            for (int i = 0; i < 12; ++i) win[i] = win[i+1];
            win[12] = LDROW(r0 + 6);
            h = r0;
        }
        for (int n = 0; n < 32; ++n) {
            float acc = 0.f;
            #pragma unroll
            for (int i = 0; i < 13; ++i) acc = fmaf(gk.k[i], win[i], acc);
            float s = acc + idenv(h) + DEF_OFF;
            qsum += fmaxf(s - sprev, 0.f);
            sprev = s;
            ++h;
            if (n < 31) {
                #pragma unroll
                for (int i = 0; i < 12; ++i) win[i] = win[i+1];
                win[12] = LDROW(h + 6);
            }
        }
    }
    segsum[ws][lane] = qsum;
    __syncthreads();
    float run = 0.f;
    for (int k = 0; k < ws; ++k) run += segsum[k][lane];

    // ---------- pass 2: recompute + write ----------
    {
        float win[13], sprev;
        int h;
        if (ws == 0) {
            #pragma unroll
            for (int i = 0; i < 13; ++i) win[i] = LDROW(-6 + i);
            sprev = 0.f; h = 0;
        } else {
            #pragma unroll
            for (int i = 0; i < 13; ++i) win[i] = LDROW(r0 - 7 + i);
            float acc = 0.f;
            #pragma unroll
            for (int i = 0; i < 13; ++i) acc = fmaf(gk.k[i], win[i], acc);
            sprev = acc + idenv(r0 - 1) + DEF_OFF;
            #pragma unroll
            for (int i = 0; i < 12; ++i) win[i] = win[i+1];
            win[12] = LDROW(r0 + 6);
            h = r0;
        }
        for (int n = 0; n < 32; ++n) {
            float acc = 0.f;
            #pragma unroll
            for (int i = 0; i < 13; ++i) acc = fmaf(gk.k[i], win[i], acc);
            float s = acc + idenv(h) + DEF_OFF;
            run += fmaxf(s - sprev, 0.f);
            sprev = s;
            float p = run - DEF_OFF - idenv(h);
            p = fminf(fmaxf(p, -BOUND), BOUND);
            float g = p + idenv(h);
            g = fminf(fmaxf(g, -1.f), 1.f);
            p2[(size_t)h*WW] = g;
            ++h;
            if (n < 31) {
                #pragma unroll
                for (int i = 0; i < 12; ++i) win[i] = win[i+1];
                win[12] = LDROW(h + 6);
            }
        }
    }
    #undef LDROW
}

// ---- bilinear grid sample: 4 px/thread, grid-x plane 0, grid-y plane 2 ----
__global__ void k_sample(const float* __restrict__ image, float* __restrict__ out) {
    int idx = blockIdx.x*256 + threadIdx.x;   // over B*H*W/4
    int w4 = idx & 127;
    int h  = (idx >> 7) & (HH-1);
    int b  = idx >> 16;
    float* ob = out + (size_t)b*3*HW;
    size_t off = (size_t)h*WW + (size_t)w4*4;
    float4 gx4 = *(const float4*)(ob + off);          // plane 0
    float4 gy4 = *(const float4*)(ob + 2*HW + off);   // plane 2
    const float* ib = image + (size_t)b*3*HW;
    const float* gxp = (const float*)&gx4;
    const float* gyp = (const float*)&gy4;
    float4 r0, r1, r2;
    float* rp[3] = {(float*)&r0, (float*)&r1, (float*)&r2};
    #pragma unroll
    for (int j = 0; j < 4; ++j) {
        float fx = (gxp[j] + 1.f) * 0.5f * (float)(WW-1);
        float fy = (gyp[j] + 1.f) * 0.5f * (float)(HH-1);
        float x0f = floorf(fx), y0f = floorf(fy);
        float wx = fx - x0f, wy = fy - y0f;
        int x0 = (int)x0f, y0 = (int)y0f;
        int x1 = x0 + 1; if (x1 > WW-1) x1 = WW-1;
        int y1 = y0 + 1; if (y1 > HH-1) y1 = HH-1;
        size_t o00 = (size_t)y0*WW + x0;
        size_t o01 = (size_t)y0*WW + x1;
        size_t o10 = (size_t)y1*WW + x0;
        size_t o11 = (size_t)y1*WW + x1;
        float w00 = (1.f-wx)*(1.f-wy), w01 = wx*(1.f-wy), w10 = (1.f-wx)*wy, w11 = wx*wy;
        #pragma unroll
        for (int c = 0; c < 3; ++c) {
            const float* ip = ib + (size_t)c*HW;
            float v = ip[o00]*w00 + ip[o01]*w01 + ip[o10]*w10 + ip[o11]*w11;
            rp[c][j] = v;
        }
    }
    *(float4*)(ob + off)          = r0;
    *(float4*)(ob + HW + off)     = r1;
    *(float4*)(ob + 2*HW + off)   = r2;
}

extern "C" void kernel_launch(void* const* d_in, const int* in_sizes, int n_in,
                              void* d_out, int out_size, void* d_ws, size_t ws_size,
                              hipStream_t stream) {
    const float* image = (const float*)d_in[0];
    const float* prim  = (const float*)d_in[1];
    float* out = (float*)d_out;

    GaussK gk;
    {
        double sigma = 13.0*0.15 + 0.35;   // 2.3
        double pdf[13], sum = 0.0;
        for (int i = 0; i < 13; ++i) {
            double t = (double)(i - 6);
            pdf[i] = exp(-0.5*(t/sigma)*(t/sigma));
            sum += pdf[i];
        }
        for (int i = 0; i < 13; ++i) gk.k[i] = (float)(pdf[i]/sum);
    }

    int nQuad = NB*HH*WW/4;               // 4,194,304
    k_vblur <<<nQuad/256, 256, 0, stream>>>(prim, out, gk);
    k_hblur <<<nQuad/256, 256, 0, stream>>>(prim, out, gk);
    k_xscan <<<NB*HH,       64, 0, stream>>>(out, gk);
    k_yscan <<<NB*8,      1024, 0, stream>>>(out, gk);
    k_sample<<<nQuad/256,  256, 0, stream>>>(image, out);
}

// Round 4
// 335.687 us; speedup vs baseline: 1.2896x; 1.2896x over previous
//
#include <hip/hip_runtime.h>
#include <math.h>

#define HH 512
#define WW 512
#define NB 64
#define HW (HH*WW)

struct GaussK { float k[13]; };

__device__ __forceinline__ float idenv(int i) {
    return (float)(2*i - (WW-1)) / (float)(WW-1);
}

#define DEF_OFF ((float)((2.0 + 4.0/511.0)/2.0))
#define BOUND   ((float)(2.0/512.0*8.0))

// ---------------- horizontal blur of prim ch1 -> out plane 1 (4 px/thread) ----------------
__global__ void k_hblur(const float* __restrict__ prim, float* __restrict__ out, GaussK gk) {
    int idx = blockIdx.x*256 + threadIdx.x;          // over B*H*W/4
    int w4 = idx & 127;
    int h  = (idx >> 7) & (HH-1);
    int b  = idx >> 16;
    const float* src = prim + ((size_t)b*2 + 1)*HW + (size_t)h*WW;
    float t[16];                                     // cols 4*w4-6 .. 4*w4+9
    #pragma unroll
    for (int j = 0; j < 16; ++j) {
        int x = w4*4 - 6 + j;
        x = x < 0 ? -x : (x > WW-1 ? 2*(WW-1) - x : x);
        t[j] = src[x];
    }
    float4 o;
    float* op = (float*)&o;
    #pragma unroll
    for (int j = 0; j < 4; ++j) {
        float acc = 0.f;
        #pragma unroll
        for (int i = 0; i < 13; ++i) acc = fmaf(gk.k[i], t[j+i], acc);
        op[j] = acc;
    }
    ((float4*)(out + ((size_t)b*3 + 1)*HW))[(size_t)h*128 + w4] = o;
}

// ---- fused vertical blur (prim ch0) + horizontal blur + row scan -> plane 0 ----
// 256 threads = 4 waves; each wave owns one (b,h) row; lane owns cols 8l..8l+7.
// No LDS: horizontal-conv halo comes from neighbor-lane shuffles; reflection at
// row edges maps back into the edge lane's own registers.
__global__ void __launch_bounds__(256) k_xscan(const float* __restrict__ prim, float* __restrict__ out, GaussK gk) {
    int lane = threadIdx.x & 63;
    int gw   = blockIdx.x*4 + (threadIdx.x >> 6);   // global wave id over B*H
    int b    = gw >> 9;
    int h    = gw & (HH-1);
    const float4* src = (const float4*)(prim + (size_t)b*2*HW);   // channel 0
    float* plane0 = out + (size_t)b*3*HW + (size_t)h*WW;

    int rows[13];
    #pragma unroll
    for (int i = 0; i < 13; ++i) {
        int r = h - 6 + i;
        rows[i] = r < 0 ? -r : (r > HH-1 ? 2*(HH-1) - r : r);
    }

    // vertical conv for own 8 columns (float4 groups 2l, 2l+1)
    float a[8];
    #pragma unroll
    for (int t = 0; t < 2; ++t) {
        int g = 2*lane + t;
        float4 acc = {0.f,0.f,0.f,0.f};
        #pragma unroll
        for (int i = 0; i < 13; ++i) {
            float4 v = src[(size_t)rows[i]*128 + g];
            acc.x = fmaf(gk.k[i], v.x, acc.x);
            acc.y = fmaf(gk.k[i], v.y, acc.y);
            acc.z = fmaf(gk.k[i], v.z, acc.z);
            acc.w = fmaf(gk.k[i], v.w, acc.w);
        }
        a[4*t+0] = acc.x; a[4*t+1] = acc.y; a[4*t+2] = acc.z; a[4*t+3] = acc.w;
    }

    // win[i] = vblur value at col 8l-7+i, i=0..20
    float win[21];
    #pragma unroll
    for (int i = 0; i < 7; ++i) {           // cols 8l-7..8l-1 from lane l-1 (a[1..7])
        float v = __shfl_up(a[i+1], 1, 64);
        win[i] = (lane == 0) ? a[7-i] : v;  // reflect: col -(7-i) -> col 7-i
    }
    #pragma unroll
    for (int i = 0; i < 8; ++i) win[7+i] = a[i];
    #pragma unroll
    for (int i = 15; i < 21; ++i) {         // cols 8l+8..8l+13 from lane l+1 (a[0..5])
        float v = __shfl_down(a[i-15], 1, 64);
        win[i] = (lane == 63) ? a[21-i] : v; // reflect: col 512+k -> col 510-k
    }

    // horizontal conv -> s at cols 8l-1 .. 8l+7
    float s[9];
    #pragma unroll
    for (int j = 0; j < 9; ++j) {
        float acc = 0.f;
        #pragma unroll
        for (int i = 0; i < 13; ++i) acc = fmaf(gk.k[i], win[j+i], acc);
        s[j] = acc + idenv(8*lane - 1 + j) + DEF_OFF;
    }
    if (lane == 0) s[0] = 0.f;              // prepend-zero boundary of the diff

    float qs[8], q = 0.f;
    #pragma unroll
    for (int j = 1; j < 9; ++j) { q += fmaxf(s[j] - s[j-1], 0.f); qs[j-1] = q; }
    float inc = q;
    #pragma unroll
    for (int d = 1; d < 64; d <<= 1) {
        float t = __shfl_up(inc, d, 64);
        if (lane >= d) inc += t;
    }
    float excl = inc - q;

    float4 g0, g1;
    float* gp0 = (float*)&g0;
    float* gp1 = (float*)&g1;
    #pragma unroll
    for (int j = 0; j < 8; ++j) {
        int wcol = lane*8 + j;
        float sx = excl + qs[j];
        float p = sx - DEF_OFF - idenv(wcol);
        p = fminf(fmaxf(p, -BOUND), BOUND);
        float g = p + idenv(wcol);
        g = fminf(fmaxf(g, -1.f), 1.f);
        if (j < 4) gp0[j] = g; else gp1[j-4] = g;
    }
    *(float4*)(plane0 + lane*8)     = g0;
    *(float4*)(plane0 + lane*8 + 4) = g1;
}

// ---- fused vertical blur + column scan (y channel): read plane 1, write plane 2 ----
// block = 1024 threads = 16 waves; wave ws owns rows [ws*32, ws*32+32)
__global__ void __launch_bounds__(1024) k_yscan(float* __restrict__ out, GaussK gk) {
    __shared__ float segsum[16][64];
    int b    = blockIdx.x >> 3;
    int wt   = blockIdx.x & 7;
    int lane = threadIdx.x & 63;
    int ws   = threadIdx.x >> 6;         // 0..15
    int w    = wt*64 + lane;
    const float* p1 = out + ((size_t)b*3 + 1)*HW + w;
    float*       p2 = out + ((size_t)b*3 + 2)*HW + w;
    int r0 = ws*32;

    #define LDROW(r_) ({ int r = (r_); r = r < 0 ? -r : (r > HH-1 ? 2*(HH-1) - r : r); \
                         p1[(size_t)r*WW]; })

    float qsum = 0.f;
    {
        float win[13], sprev;
        int h;
        if (ws == 0) {
            #pragma unroll
            for (int i = 0; i < 13; ++i) win[i] = LDROW(-6 + i);
            sprev = 0.f; h = 0;
        } else {
            #pragma unroll
            for (int i = 0; i < 13; ++i) win[i] = LDROW(r0 - 7 + i);
            float acc = 0.f;
            #pragma unroll
            for (int i = 0; i < 13; ++i) acc = fmaf(gk.k[i], win[i], acc);
            sprev = acc + idenv(r0 - 1) + DEF_OFF;
            #pragma unroll
            for (int i = 0; i < 12; ++i) win[i] = win[i+1];
            win[12] = LDROW(r0 + 6);
            h = r0;
        }
        for (int n = 0; n < 32; ++n) {
            float acc = 0.f;
            #pragma unroll
            for (int i = 0; i < 13; ++i) acc = fmaf(gk.k[i], win[i], acc);
            float s = acc + idenv(h) + DEF_OFF;
            qsum += fmaxf(s - sprev, 0.f);
            sprev = s;
            ++h;
            if (n < 31) {
                #pragma unroll
                for (int i = 0; i < 12; ++i) win[i] = win[i+1];
                win[12] = LDROW(h + 6);
            }
        }
    }
    segsum[ws][lane] = qsum;
    __syncthreads();
    float run = 0.f;
    for (int k = 0; k < ws; ++k) run += segsum[k][lane];

    {
        float win[13], sprev;
        int h;
        if (ws == 0) {
            #pragma unroll
            for (int i = 0; i < 13; ++i) win[i] = LDROW(-6 + i);
            sprev = 0.f; h = 0;
        } else {
            #pragma unroll
            for (int i = 0; i < 13; ++i) win[i] = LDROW(r0 - 7 + i);
            float acc = 0.f;
            #pragma unroll
            for (int i = 0; i < 13; ++i) acc = fmaf(gk.k[i], win[i], acc);
            sprev = acc + idenv(r0 - 1) + DEF_OFF;
            #pragma unroll
            for (int i = 0; i < 12; ++i) win[i] = win[i+1];
            win[12] = LDROW(r0 + 6);
            h = r0;
        }
        for (int n = 0; n < 32; ++n) {
            float acc = 0.f;
            #pragma unroll
            for (int i = 0; i < 13; ++i) acc = fmaf(gk.k[i], win[i], acc);
            float s = acc + idenv(h) + DEF_OFF;
            run += fmaxf(s - sprev, 0.f);
            sprev = s;
            float p = run - DEF_OFF - idenv(h);
            p = fminf(fmaxf(p, -BOUND), BOUND);
            float g = p + idenv(h);
            g = fminf(fmaxf(g, -1.f), 1.f);
            p2[(size_t)h*WW] = g;
            ++h;
            if (n < 31) {
                #pragma unroll
                for (int i = 0; i < 12; ++i) win[i] = win[i+1];
                win[12] = LDROW(h + 6);
            }
        }
    }
    #undef LDROW
}

// ---- bilinear grid sample: 1 px/lane, 2 independent pixels (b, b+32) per thread ----
__global__ void __launch_bounds__(256) k_sample(const float* __restrict__ image, float* __restrict__ out) {
    int idx = blockIdx.x*256 + threadIdx.x;   // over 32*H*W
    int w  = idx & (WW-1);
    int h  = (idx >> 9) & (HH-1);
    int b0 = idx >> 18;                        // 0..31
    int off = h*WW + w;

    const float* ib[2];
    float* ob[2];
    int o00[2], o01[2], o10[2], o11[2];
    float w00[2], w01[2], w10[2], w11[2];

    #pragma unroll
    for (int u = 0; u < 2; ++u) {
        int b = b0 + 32*u;
        ob[u] = out   + (size_t)b*3*HW;
        ib[u] = image + (size_t)b*3*HW;
        float gx = __builtin_nontemporal_load(ob[u] + off);
        float gy = __builtin_nontemporal_load(ob[u] + 2*HW + off);
        float fx = (gx + 1.f) * 0.5f * (float)(WW-1);
        float fy = (gy + 1.f) * 0.5f * (float)(HH-1);
        float x0f = floorf(fx), y0f = floorf(fy);
        float wx = fx - x0f, wy = fy - y0f;
        int x0 = (int)x0f, y0 = (int)y0f;
        int x1 = x0 + 1; if (x1 > WW-1) x1 = WW-1;
        int y1 = y0 + 1; if (y1 > HH-1) y1 = HH-1;
        o00[u] = y0*WW + x0;
        o01[u] = y0*WW + x1;
        o10[u] = y1*WW + x0;
        o11[u] = y1*WW + x1;
        w00[u] = (1.f-wx)*(1.f-wy); w01[u] = wx*(1.f-wy);
        w10[u] = (1.f-wx)*wy;       w11[u] = wx*wy;
    }

    float v00[2][3], v01[2][3], v10[2][3], v11[2][3];
    #pragma unroll
    for (int u = 0; u < 2; ++u) {
        #pragma unroll
        for (int c = 0; c < 3; ++c) {
            const float* p = ib[u] + (size_t)c*HW;
            v00[u][c] = p[o00[u]];
            v01[u][c] = p[o01[u]];
            v10[u][c] = p[o10[u]];
            v11[u][c] = p[o11[u]];
        }
    }
    #pragma unroll
    for (int u = 0; u < 2; ++u) {
        #pragma unroll
        for (int c = 0; c < 3; ++c) {
            float r = v00[u][c]*w00[u] + v01[u][c]*w01[u]
                    + v10[u][c]*w10[u] + v11[u][c]*w11[u];
            __builtin_nontemporal_store(r, ob[u] + (size_t)c*HW + off);
        }
    }
}

extern "C" void kernel_launch(void* const* d_in, const int* in_sizes, int n_in,
                              void* d_out, int out_size, void* d_ws, size_t ws_size,
                              hipStream_t stream) {
    const float* image = (const float*)d_in[0];
    const float* prim  = (const float*)d_in[1];
    float* out = (float*)d_out;

    GaussK gk;
    {
        double sigma = 13.0*0.15 + 0.35;   // 2.3
        double pdf[13], sum = 0.0;
        for (int i = 0; i < 13; ++i) {
            double t = (double)(i - 6);
            pdf[i] = exp(-0.5*(t/sigma)*(t/sigma));
            sum += pdf[i];
        }
        for (int i = 0; i < 13; ++i) gk.k[i] = (float)(pdf[i]/sum);
    }

    int nQuad = NB*HH*WW/4;               // 4,194,304
    k_hblur <<<nQuad/256,      256, 0, stream>>>(prim, out, gk);
    k_xscan <<<NB*HH/4,        256, 0, stream>>>(prim, out, gk);
    k_yscan <<<NB*8,          1024, 0, stream>>>(out, gk);
    k_sample<<<NB*HH*WW/2/256, 256, 0, stream>>>(image, out);
}